// Round 2
// baseline (1436.748 us; speedup 1.0000x reference)
//
#include <hip/hip_runtime.h>

#define N_NODES 50000
#define N_EDGES 1600000
#define IN_CH   256
#define ADP     64
#define EDGE_DIM 32

// ---------------- K0: degree histogram over src nodes ------------------------
__global__ __launch_bounds__(256) void k_hist(const int* __restrict__ ei_src,
                                              int* __restrict__ deg) {
    int i = blockIdx.x * 256 + threadIdx.x;
    int stride = gridDim.x * 256;
    for (; i < N_EDGES; i += stride) atomicAdd(&deg[ei_src[i]], 1);
}

// ---------------- K1: exclusive prefix sum -> offsets, cursor ----------------
// Single block of 256; each thread owns a 196-node chunk; thread 0 scans the
// 256 partials serially (256 LDS ops, ~µs).
__global__ __launch_bounds__(256) void k_scan(const int* __restrict__ deg,
                                              int* __restrict__ offs,
                                              int* __restrict__ cursor) {
    __shared__ int ps[256];
    int tid = threadIdx.x;
    const int CH = (N_NODES + 255) / 256;  // 196
    int base = tid * CH;
    int s = 0;
    for (int i = 0; i < CH; i++) {
        int idx = base + i;
        if (idx < N_NODES) s += deg[idx];
    }
    ps[tid] = s;
    __syncthreads();
    if (tid == 0) {
        int run = 0;
        for (int i = 0; i < 256; i++) { int t = ps[i]; ps[i] = run; run += t; }
    }
    __syncthreads();
    int run = ps[tid];
    for (int i = 0; i < CH; i++) {
        int idx = base + i;
        if (idx < N_NODES) { offs[idx] = run; cursor[idx] = run; run += deg[idx]; }
    }
}

// ---------------- K2: bucket edge ids by src ---------------------------------
__global__ __launch_bounds__(256) void k_scatter(const int* __restrict__ ei_src,
                                                 int* __restrict__ cursor,
                                                 int* __restrict__ elist) {
    int i = blockIdx.x * 256 + threadIdx.x;
    int stride = gridDim.x * 256;
    for (; i < N_EDGES; i += stride) {
        int s = ei_src[i];
        int pos = atomicAdd(&cursor[s], 1);
        elist[pos] = i;
    }
}

// ---------------- K3: gather + time-proj + mean (NO f32 atomics) -------------
// One wave per node. Lane c holds W_time row c (32 VGPRs). Edge attr read as
// wave-uniform float4 broadcasts. Mean written directly.
__global__ __launch_bounds__(256) void k_gather(const float* __restrict__ ea,
                                                const int* __restrict__ offs,
                                                const int* __restrict__ deg,
                                                const int* __restrict__ elist,
                                                const float* __restrict__ Wt,
                                                const float* __restrict__ bt,
                                                float* __restrict__ ntf) {
    int lane = threadIdx.x & 63;
    int wv   = threadIdx.x >> 6;
    float w[EDGE_DIM];
    {
        const float4* w4 = (const float4*)(Wt + (size_t)lane * EDGE_DIM);
        #pragma unroll
        for (int k4 = 0; k4 < EDGE_DIM / 4; k4++) {
            float4 v = w4[k4];
            w[4 * k4 + 0] = v.x; w[4 * k4 + 1] = v.y;
            w[4 * k4 + 2] = v.z; w[4 * k4 + 3] = v.w;
        }
    }
    float b = bt[lane];
    int n = blockIdx.x * 4 + wv;
    int nstride = gridDim.x * 4;
    for (; n < N_NODES; n += nstride) {
        int st = offs[n];
        int d  = deg[n];
        float acc = 0.f;
        for (int i = 0; i < d; i++) {
            int e = elist[st + i];
            const float4* a4 = (const float4*)(ea + (size_t)e * EDGE_DIM);
            float s = b;
            #pragma unroll
            for (int k4 = 0; k4 < EDGE_DIM / 4; k4++) {
                float4 v = a4[k4];
                s += v.x * w[4 * k4 + 0] + v.y * w[4 * k4 + 1]
                   + v.z * w[4 * k4 + 2] + v.w * w[4 * k4 + 3];
            }
            acc += fmaxf(s, 0.f);
        }
        ntf[(size_t)n * ADP + lane] = acc / fmaxf((float)d, 1.f);
    }
}

// ---------------- K4: node_feat = relu(x @ W_down^T + b_down) ----------------
// W_down swizzled in 64KB LDS; 4-node register blocking shares each LDS weight
// read across 4 FMAs (LDS-pipe was the limit).
__global__ __launch_bounds__(256) void k_down(const float* __restrict__ x,
                                              const float* __restrict__ Wd,
                                              const float* __restrict__ bd,
                                              float* __restrict__ nfeat) {
    __shared__ float lds[IN_CH * ADP];  // 64KB
    for (int idx = threadIdx.x; idx < IN_CH * ADP; idx += 256) {
        int c = idx >> 8;
        int k = idx & 255;
        lds[k * ADP + (c ^ (k & 31))] = Wd[idx];
    }
    __syncthreads();
    int wv = threadIdx.x >> 6;
    int lane = threadIdx.x & 63;
    float b = bd[lane];
    int g = blockIdx.x * 4 + wv;
    int gstride = gridDim.x * 4;
    for (; g < N_NODES / 4; g += gstride) {   // 50000 % 4 == 0
        int n0 = g * 4;
        const float4* r0 = (const float4*)(x + (size_t)(n0 + 0) * IN_CH);
        const float4* r1 = (const float4*)(x + (size_t)(n0 + 1) * IN_CH);
        const float4* r2 = (const float4*)(x + (size_t)(n0 + 2) * IN_CH);
        const float4* r3 = (const float4*)(x + (size_t)(n0 + 3) * IN_CH);
        float a0 = b, a1 = b, a2 = b, a3 = b;
        #pragma unroll 4
        for (int k4 = 0; k4 < IN_CH / 4; k4++) {
            float4 v0 = r0[k4], v1 = r1[k4], v2 = r2[k4], v3 = r3[k4];
            const float* p0 = (const float*)&v0;
            const float* p1 = (const float*)&v1;
            const float* p2 = (const float*)&v2;
            const float* p3 = (const float*)&v3;
            #pragma unroll
            for (int j = 0; j < 4; j++) {
                int k = 4 * k4 + j;
                float wv_ = lds[k * ADP + (lane ^ (k & 31))];
                a0 += p0[j] * wv_;
                a1 += p1[j] * wv_;
                a2 += p2[j] * wv_;
                a3 += p3[j] * wv_;
            }
        }
        nfeat[(size_t)(n0 + 0) * ADP + lane] = fmaxf(a0, 0.f);
        nfeat[(size_t)(n0 + 1) * ADP + lane] = fmaxf(a1, 0.f);
        nfeat[(size_t)(n0 + 2) * ADP + lane] = fmaxf(a2, 0.f);
        nfeat[(size_t)(n0 + 3) * ADP + lane] = fmaxf(a3, 0.f);
    }
}

// ---------------- K5: fused = relu(W_fusion @ [nf | ntf] + b) ----------------
// ntf already holds the mean. Same 4-node blocking + float4 uniform loads.
__global__ __launch_bounds__(256) void k_fuse(const float* __restrict__ nfeat,
                                              const float* __restrict__ ntf,
                                              const float* __restrict__ Wf,
                                              const float* __restrict__ bf,
                                              float* __restrict__ fused) {
    __shared__ float lds[2 * ADP * ADP];  // 32KB, [k(128)][c(64)] swizzled
    for (int idx = threadIdx.x; idx < 2 * ADP * ADP; idx += 256) {
        int c = idx >> 7;
        int k = idx & 127;
        lds[k * ADP + (c ^ (k & 31))] = Wf[idx];
    }
    __syncthreads();
    int wv = threadIdx.x >> 6;
    int lane = threadIdx.x & 63;
    float b = bf[lane];
    int g = blockIdx.x * 4 + wv;
    int gstride = gridDim.x * 4;
    for (; g < N_NODES / 4; g += gstride) {
        int n0 = g * 4;
        float a0 = b, a1 = b, a2 = b, a3 = b;
        const float4* f0 = (const float4*)(nfeat + (size_t)(n0 + 0) * ADP);
        const float4* f1 = (const float4*)(nfeat + (size_t)(n0 + 1) * ADP);
        const float4* f2 = (const float4*)(nfeat + (size_t)(n0 + 2) * ADP);
        const float4* f3 = (const float4*)(nfeat + (size_t)(n0 + 3) * ADP);
        #pragma unroll 2
        for (int k4 = 0; k4 < ADP / 4; k4++) {
            float4 v0 = f0[k4], v1 = f1[k4], v2 = f2[k4], v3 = f3[k4];
            const float* p0 = (const float*)&v0;
            const float* p1 = (const float*)&v1;
            const float* p2 = (const float*)&v2;
            const float* p3 = (const float*)&v3;
            #pragma unroll
            for (int j = 0; j < 4; j++) {
                int k = 4 * k4 + j;
                float wv_ = lds[k * ADP + (lane ^ (k & 31))];
                a0 += p0[j] * wv_;
                a1 += p1[j] * wv_;
                a2 += p2[j] * wv_;
                a3 += p3[j] * wv_;
            }
        }
        const float4* t0 = (const float4*)(ntf + (size_t)(n0 + 0) * ADP);
        const float4* t1 = (const float4*)(ntf + (size_t)(n0 + 1) * ADP);
        const float4* t2 = (const float4*)(ntf + (size_t)(n0 + 2) * ADP);
        const float4* t3 = (const float4*)(ntf + (size_t)(n0 + 3) * ADP);
        #pragma unroll 2
        for (int k4 = 0; k4 < ADP / 4; k4++) {
            float4 v0 = t0[k4], v1 = t1[k4], v2 = t2[k4], v3 = t3[k4];
            const float* p0 = (const float*)&v0;
            const float* p1 = (const float*)&v1;
            const float* p2 = (const float*)&v2;
            const float* p3 = (const float*)&v3;
            #pragma unroll
            for (int j = 0; j < 4; j++) {
                int k = 4 * k4 + j + ADP;
                float wv_ = lds[k * ADP + (lane ^ (k & 31))];
                a0 += p0[j] * wv_;
                a1 += p1[j] * wv_;
                a2 += p2[j] * wv_;
                a3 += p3[j] * wv_;
            }
        }
        fused[(size_t)(n0 + 0) * ADP + lane] = fmaxf(a0, 0.f);
        fused[(size_t)(n0 + 1) * ADP + lane] = fmaxf(a1, 0.f);
        fused[(size_t)(n0 + 2) * ADP + lane] = fmaxf(a2, 0.f);
        fused[(size_t)(n0 + 3) * ADP + lane] = fmaxf(a3, 0.f);
    }
}

// ---------------- K6: out = x + fused @ W_up^T + b_up ------------------------
__global__ __launch_bounds__(256) void k_up(const float* __restrict__ fused,
                                            const float* __restrict__ x,
                                            const float* __restrict__ Wu,
                                            const float* __restrict__ bu,
                                            float* __restrict__ out) {
    int t = threadIdx.x;
    float w[ADP];
    {
        const float4* w4 = (const float4*)(Wu + (size_t)t * ADP);
        #pragma unroll
        for (int k4 = 0; k4 < ADP / 4; k4++) {
            float4 v = w4[k4];
            w[4 * k4 + 0] = v.x; w[4 * k4 + 1] = v.y;
            w[4 * k4 + 2] = v.z; w[4 * k4 + 3] = v.w;
        }
    }
    float b = bu[t];
    for (int n = blockIdx.x; n < N_NODES; n += gridDim.x) {
        const float4* f4 = (const float4*)(fused + (size_t)n * ADP);
        float acc = b;
        #pragma unroll
        for (int k4 = 0; k4 < ADP / 4; k4++) {
            float4 v = f4[k4];
            acc += v.x * w[4 * k4 + 0] + v.y * w[4 * k4 + 1]
                 + v.z * w[4 * k4 + 2] + v.w * w[4 * k4 + 3];
        }
        size_t off = (size_t)n * IN_CH + t;
        out[off] = x[off] + acc;
    }
}

extern "C" void kernel_launch(void* const* d_in, const int* in_sizes, int n_in,
                              void* d_out, int out_size, void* d_ws, size_t ws_size,
                              hipStream_t stream) {
    const float* x   = (const float*)d_in[0];
    const int*   ei  = (const int*)d_in[1];     // [2, E]; row 0 = src
    const float* ea  = (const float*)d_in[2];
    const float* Wd  = (const float*)d_in[3];
    const float* bd  = (const float*)d_in[4];
    const float* Wt  = (const float*)d_in[5];
    const float* bt  = (const float*)d_in[6];
    const float* Wf  = (const float*)d_in[7];
    const float* bf  = (const float*)d_in[8];
    const float* Wu  = (const float*)d_in[9];
    const float* bu  = (const float*)d_in[10];
    float* out = (float*)d_out;

    // ws layout
    int* deg    = (int*)d_ws;                       // [N]
    int* cursor = deg + N_NODES;                    // [N]
    int* offs   = cursor + N_NODES;                 // [N]
    int* elist  = offs + N_NODES;                   // [E]
    float* ntf   = (float*)(elist + N_EDGES);       // [N*64] mean time feat
    float* nfeat = ntf + (size_t)N_NODES * ADP;     // [N*64]
    float* fused = nfeat + (size_t)N_NODES * ADP;   // [N*64]

    hipMemsetAsync(deg, 0, N_NODES * sizeof(int), stream);

    k_hist   <<<2048, 256, 0, stream>>>(ei, deg);
    k_scan   <<<   1, 256, 0, stream>>>(deg, offs, cursor);
    k_scatter<<<2048, 256, 0, stream>>>(ei, cursor, elist);
    k_gather <<<2048, 256, 0, stream>>>(ea, offs, deg, elist, Wt, bt, ntf);
    k_down   <<<1024, 256, 0, stream>>>(x, Wd, bd, nfeat);
    k_fuse   <<<1024, 256, 0, stream>>>(nfeat, ntf, Wf, bf, fused);
    k_up     <<<8192, 256, 0, stream>>>(fused, x, Wu, bu, out);
}

// Round 3
// 938.106 us; speedup vs baseline: 1.5315x; 1.5315x over previous
//
#include <hip/hip_runtime.h>

#define N_NODES 50000
#define N_EDGES 1600000
#define IN_CH   256
#define ADP     64
#define EDGE_DIM 32
#define NB_SCAN 196   // ceil(50000/256)

// ---------------- K0: degree histogram over src nodes ------------------------
__global__ __launch_bounds__(256) void k_hist(const int* __restrict__ ei_src,
                                              int* __restrict__ deg) {
    int i = blockIdx.x * 256 + threadIdx.x;
    if (i < N_EDGES) atomicAdd(&deg[ei_src[i]], 1);
}

// ---------------- K1a: per-block degree sums ---------------------------------
__global__ __launch_bounds__(256) void k_bsum(const int* __restrict__ deg,
                                              int* __restrict__ bsum) {
    __shared__ int wsum[4];
    int idx = blockIdx.x * 256 + threadIdx.x;
    int v = (idx < N_NODES) ? deg[idx] : 0;
    for (int o = 32; o > 0; o >>= 1) v += __shfl_down(v, o, 64);
    if ((threadIdx.x & 63) == 0) wsum[threadIdx.x >> 6] = v;
    __syncthreads();
    if (threadIdx.x == 0) bsum[blockIdx.x] = wsum[0] + wsum[1] + wsum[2] + wsum[3];
}

// ---------------- K1b: scan the 196 block sums (1 block) ---------------------
__global__ __launch_bounds__(256) void k_bscan(const int* __restrict__ bsum,
                                               int* __restrict__ bpre) {
    __shared__ int a[256], b[256];
    int t = threadIdx.x;
    int v = (t < NB_SCAN) ? bsum[t] : 0;
    a[t] = v; __syncthreads();
    int* src = a; int* dst = b;
    for (int o = 1; o < 256; o <<= 1) {
        int x = src[t]; if (t >= o) x += src[t - o];
        dst[t] = x; __syncthreads();
        int* tmp = src; src = dst; dst = tmp;
    }
    if (t < NB_SCAN) bpre[t] = src[t] - v;   // exclusive prefix of block sums
}

// ---------------- K1c: per-node exclusive offsets ----------------------------
__global__ __launch_bounds__(256) void k_offs(const int* __restrict__ deg,
                                              const int* __restrict__ bpre,
                                              int* __restrict__ offs,
                                              int* __restrict__ cursor) {
    __shared__ int a[256], b[256];
    int t = threadIdx.x;
    int idx = blockIdx.x * 256 + t;
    int v = (idx < N_NODES) ? deg[idx] : 0;
    a[t] = v; __syncthreads();
    int* src = a; int* dst = b;
    for (int o = 1; o < 256; o <<= 1) {
        int x = src[t]; if (t >= o) x += src[t - o];
        dst[t] = x; __syncthreads();
        int* tmp = src; src = dst; dst = tmp;
    }
    if (idx < N_NODES) {
        int e = bpre[blockIdx.x] + src[t] - v;
        offs[idx] = e; cursor[idx] = e;
    }
}

// ---------------- K2: bucket edge ids by src ---------------------------------
__global__ __launch_bounds__(256) void k_scatter(const int* __restrict__ ei_src,
                                                 int* __restrict__ cursor,
                                                 int* __restrict__ elist) {
    int i = blockIdx.x * 256 + threadIdx.x;
    if (i < N_EDGES) {
        int s = ei_src[i];
        elist[atomicAdd(&cursor[s], 1)] = i;
    }
}

// ---------------- K3: gather + time-proj + mean ------------------------------
// One wave per node. Per 8-edge chunk: ONE coalesced gather instruction
// (64 lanes x float4 = 8 random 128B rows, high MLP) -> LDS stage ->
// 8 broadcast ds_read_b128 + 32 FMA per edge. No f32 atomics, no tf array.
__global__ __launch_bounds__(256) void k_gatherproj(const float* __restrict__ ea,
                                                    const int* __restrict__ offs,
                                                    const int* __restrict__ deg,
                                                    const int* __restrict__ elist,
                                                    const float* __restrict__ Wt,
                                                    const float* __restrict__ bt,
                                                    float* __restrict__ ntf) {
    __shared__ float4 buf[4][8][8];   // [wave][edge-in-chunk][float4 seg] = 4KB
    int t = threadIdx.x;
    int lane = t & 63, wv = t >> 6;
    float w[EDGE_DIM];
    {
        const float4* w4 = (const float4*)(Wt + (size_t)lane * EDGE_DIM);
        #pragma unroll
        for (int k4 = 0; k4 < 8; k4++) {
            float4 v = w4[k4];
            w[4*k4+0] = v.x; w[4*k4+1] = v.y; w[4*k4+2] = v.z; w[4*k4+3] = v.w;
        }
    }
    float bias = bt[lane];
    int n = blockIdx.x * 4 + wv;
    if (n >= N_NODES) return;
    int st = offs[n], d = deg[n];
    int sub = lane >> 3;   // edge slot 0..7
    int seg = lane & 7;    // float4 within row
    float acc = 0.f;
    for (int base = 0; base < d; base += 8) {
        int cnt = min(8, d - base);
        int ei_ = base + (sub < cnt ? sub : cnt - 1);
        int e = elist[st + ei_];                       // broadcast per 8 lanes
        buf[wv][sub][seg] = ((const float4*)ea)[(size_t)e * 8 + seg];
        #pragma unroll 1
        for (int j = 0; j < cnt; j++) {
            float s0 = bias, s1 = 0.f;
            #pragma unroll
            for (int k4 = 0; k4 < 8; k4 += 2) {
                float4 v0 = buf[wv][j][k4];
                float4 v1 = buf[wv][j][k4 + 1];
                s0 += v0.x*w[4*k4+0] + v0.y*w[4*k4+1] + v0.z*w[4*k4+2] + v0.w*w[4*k4+3];
                s1 += v1.x*w[4*k4+4] + v1.y*w[4*k4+5] + v1.z*w[4*k4+6] + v1.w*w[4*k4+7];
            }
            acc += fmaxf(s0 + s1, 0.f);
        }
    }
    ntf[(size_t)n * ADP + lane] = acc / fmaxf((float)d, 1.f);
}

// ---------------- K4: node_feat = relu(x @ W_down^T + b_down) ----------------
__global__ __launch_bounds__(256) void k_down(const float* __restrict__ x,
                                              const float* __restrict__ Wd,
                                              const float* __restrict__ bd,
                                              float* __restrict__ nfeat) {
    __shared__ float lds[IN_CH * ADP];  // 64KB
    for (int idx = threadIdx.x; idx < IN_CH * ADP; idx += 256) {
        int c = idx >> 8;
        int k = idx & 255;
        lds[k * ADP + (c ^ (k & 31))] = Wd[idx];
    }
    __syncthreads();
    int wv = threadIdx.x >> 6;
    int lane = threadIdx.x & 63;
    float b = bd[lane];
    int g = blockIdx.x * 4 + wv;
    int gstride = gridDim.x * 4;
    for (; g < N_NODES / 4; g += gstride) {
        int n0 = g * 4;
        const float4* r0 = (const float4*)(x + (size_t)(n0 + 0) * IN_CH);
        const float4* r1 = (const float4*)(x + (size_t)(n0 + 1) * IN_CH);
        const float4* r2 = (const float4*)(x + (size_t)(n0 + 2) * IN_CH);
        const float4* r3 = (const float4*)(x + (size_t)(n0 + 3) * IN_CH);
        float a0 = b, a1 = b, a2 = b, a3 = b;
        #pragma unroll 4
        for (int k4 = 0; k4 < IN_CH / 4; k4++) {
            float4 v0 = r0[k4], v1 = r1[k4], v2 = r2[k4], v3 = r3[k4];
            const float* p0 = (const float*)&v0;
            const float* p1 = (const float*)&v1;
            const float* p2 = (const float*)&v2;
            const float* p3 = (const float*)&v3;
            #pragma unroll
            for (int j = 0; j < 4; j++) {
                int k = 4 * k4 + j;
                float wv_ = lds[k * ADP + (lane ^ (k & 31))];
                a0 += p0[j] * wv_;
                a1 += p1[j] * wv_;
                a2 += p2[j] * wv_;
                a3 += p3[j] * wv_;
            }
        }
        nfeat[(size_t)(n0 + 0) * ADP + lane] = fmaxf(a0, 0.f);
        nfeat[(size_t)(n0 + 1) * ADP + lane] = fmaxf(a1, 0.f);
        nfeat[(size_t)(n0 + 2) * ADP + lane] = fmaxf(a2, 0.f);
        nfeat[(size_t)(n0 + 3) * ADP + lane] = fmaxf(a3, 0.f);
    }
}

// ---------------- K5: fused = relu(W_fusion @ [nf | ntf] + b) ----------------
__global__ __launch_bounds__(256) void k_fuse(const float* __restrict__ nfeat,
                                              const float* __restrict__ ntf,
                                              const float* __restrict__ Wf,
                                              const float* __restrict__ bf,
                                              float* __restrict__ fused) {
    __shared__ float lds[2 * ADP * ADP];  // 32KB
    for (int idx = threadIdx.x; idx < 2 * ADP * ADP; idx += 256) {
        int c = idx >> 7;
        int k = idx & 127;
        lds[k * ADP + (c ^ (k & 31))] = Wf[idx];
    }
    __syncthreads();
    int wv = threadIdx.x >> 6;
    int lane = threadIdx.x & 63;
    float b = bf[lane];
    int g = blockIdx.x * 4 + wv;
    int gstride = gridDim.x * 4;
    for (; g < N_NODES / 4; g += gstride) {
        int n0 = g * 4;
        float a0 = b, a1 = b, a2 = b, a3 = b;
        const float4* f0 = (const float4*)(nfeat + (size_t)(n0 + 0) * ADP);
        const float4* f1 = (const float4*)(nfeat + (size_t)(n0 + 1) * ADP);
        const float4* f2 = (const float4*)(nfeat + (size_t)(n0 + 2) * ADP);
        const float4* f3 = (const float4*)(nfeat + (size_t)(n0 + 3) * ADP);
        #pragma unroll 2
        for (int k4 = 0; k4 < ADP / 4; k4++) {
            float4 v0 = f0[k4], v1 = f1[k4], v2 = f2[k4], v3 = f3[k4];
            const float* p0 = (const float*)&v0;
            const float* p1 = (const float*)&v1;
            const float* p2 = (const float*)&v2;
            const float* p3 = (const float*)&v3;
            #pragma unroll
            for (int j = 0; j < 4; j++) {
                int k = 4 * k4 + j;
                float wv_ = lds[k * ADP + (lane ^ (k & 31))];
                a0 += p0[j] * wv_;
                a1 += p1[j] * wv_;
                a2 += p2[j] * wv_;
                a3 += p3[j] * wv_;
            }
        }
        const float4* t0 = (const float4*)(ntf + (size_t)(n0 + 0) * ADP);
        const float4* t1 = (const float4*)(ntf + (size_t)(n0 + 1) * ADP);
        const float4* t2 = (const float4*)(ntf + (size_t)(n0 + 2) * ADP);
        const float4* t3 = (const float4*)(ntf + (size_t)(n0 + 3) * ADP);
        #pragma unroll 2
        for (int k4 = 0; k4 < ADP / 4; k4++) {
            float4 v0 = t0[k4], v1 = t1[k4], v2 = t2[k4], v3 = t3[k4];
            const float* p0 = (const float*)&v0;
            const float* p1 = (const float*)&v1;
            const float* p2 = (const float*)&v2;
            const float* p3 = (const float*)&v3;
            #pragma unroll
            for (int j = 0; j < 4; j++) {
                int k = 4 * k4 + j + ADP;
                float wv_ = lds[k * ADP + (lane ^ (k & 31))];
                a0 += p0[j] * wv_;
                a1 += p1[j] * wv_;
                a2 += p2[j] * wv_;
                a3 += p3[j] * wv_;
            }
        }
        fused[(size_t)(n0 + 0) * ADP + lane] = fmaxf(a0, 0.f);
        fused[(size_t)(n0 + 1) * ADP + lane] = fmaxf(a1, 0.f);
        fused[(size_t)(n0 + 2) * ADP + lane] = fmaxf(a2, 0.f);
        fused[(size_t)(n0 + 3) * ADP + lane] = fmaxf(a3, 0.f);
    }
}

// ---------------- K6: out = x + fused @ W_up^T + b_up ------------------------
__global__ __launch_bounds__(256) void k_up(const float* __restrict__ fused,
                                            const float* __restrict__ x,
                                            const float* __restrict__ Wu,
                                            const float* __restrict__ bu,
                                            float* __restrict__ out) {
    int t = threadIdx.x;
    float w[ADP];
    {
        const float4* w4 = (const float4*)(Wu + (size_t)t * ADP);
        #pragma unroll
        for (int k4 = 0; k4 < ADP / 4; k4++) {
            float4 v = w4[k4];
            w[4*k4+0] = v.x; w[4*k4+1] = v.y; w[4*k4+2] = v.z; w[4*k4+3] = v.w;
        }
    }
    float b = bu[t];
    for (int n = blockIdx.x; n < N_NODES; n += gridDim.x) {
        const float4* f4 = (const float4*)(fused + (size_t)n * ADP);
        float acc = b;
        #pragma unroll
        for (int k4 = 0; k4 < ADP / 4; k4++) {
            float4 v = f4[k4];
            acc += v.x*w[4*k4+0] + v.y*w[4*k4+1] + v.z*w[4*k4+2] + v.w*w[4*k4+3];
        }
        size_t off = (size_t)n * IN_CH + t;
        out[off] = x[off] + acc;
    }
}

extern "C" void kernel_launch(void* const* d_in, const int* in_sizes, int n_in,
                              void* d_out, int out_size, void* d_ws, size_t ws_size,
                              hipStream_t stream) {
    const float* x   = (const float*)d_in[0];
    const int*   ei  = (const int*)d_in[1];     // [2, E]; row 0 = src
    const float* ea  = (const float*)d_in[2];
    const float* Wd  = (const float*)d_in[3];
    const float* bd  = (const float*)d_in[4];
    const float* Wt  = (const float*)d_in[5];
    const float* bt  = (const float*)d_in[6];
    const float* Wf  = (const float*)d_in[7];
    const float* bf  = (const float*)d_in[8];
    const float* Wu  = (const float*)d_in[9];
    const float* bu  = (const float*)d_in[10];
    float* out = (float*)d_out;

    // ws layout
    int* deg    = (int*)d_ws;                       // [N]
    int* offs   = deg + N_NODES;                    // [N]
    int* cursor = offs + N_NODES;                   // [N]
    int* bsum   = cursor + N_NODES;                 // [256]
    int* bpre   = bsum + 256;                       // [256]
    int* elist  = bpre + 256;                       // [E]
    float* ntf   = (float*)(elist + N_EDGES);       // [N*64]
    float* nfeat = ntf + (size_t)N_NODES * ADP;     // [N*64]
    float* fused = nfeat + (size_t)N_NODES * ADP;   // [N*64]

    hipMemsetAsync(deg, 0, N_NODES * sizeof(int), stream);

    k_hist      <<< 6250, 256, 0, stream>>>(ei, deg);
    k_bsum      <<<NB_SCAN, 256, 0, stream>>>(deg, bsum);
    k_bscan     <<<    1, 256, 0, stream>>>(bsum, bpre);
    k_offs      <<<NB_SCAN, 256, 0, stream>>>(deg, bpre, offs, cursor);
    k_scatter   <<< 6250, 256, 0, stream>>>(ei, cursor, elist);
    k_gatherproj<<<12500, 256, 0, stream>>>(ea, offs, deg, elist, Wt, bt, ntf);
    k_down      <<< 1024, 256, 0, stream>>>(x, Wd, bd, nfeat);
    k_fuse      <<< 1024, 256, 0, stream>>>(nfeat, ntf, Wf, bf, fused);
    k_up        <<< 8192, 256, 0, stream>>>(fused, x, Wu, bu, out);
}